// Round 1
// baseline (805.427 us; speedup 1.0000x reference)
//
#include <hip/hip_runtime.h>
#include <hip/hip_bf16.h>

// Fused MHA+RoPE pipeline for MI355X (gfx950), bf16 MFMA throughout.
// Shapes fixed per reference: B=4, S=2048, E=2048, H=16, D=128, M=B*S=8192.
//
// ws layout (192 MB):
//   [0,32M)    xq16   (bf16 x_q)        -> later reused as Vt [BH][D][S]
//   [32,64M)   xkv16                    -> later reused as attn16 [M][E]
//   [64,96M)   wq16,wk16,wv16,wo16 (8MB each)
//   [96,128M)  q0 [B,S,H,D] bf16 (roped in place)
//   [128,160M) k0 (roped in place if k_rope)
//   [160,192M) v0

typedef __bf16 bf16;
typedef __bf16 bf16x8 __attribute__((ext_vector_type(8)));
typedef float  f32x4  __attribute__((ext_vector_type(4)));

constexpr int Bc = 4, Sc = 2048, Ec = 2048, Hc = 16, Dc = 128;
constexpr int Mc = Bc * Sc; // 8192

__device__ __forceinline__ void async16(const void* g, void* l) {
  __builtin_amdgcn_global_load_lds(
      (const __attribute__((address_space(1))) void*)g,
      (__attribute__((address_space(3))) void*)l, 16, 0, 0);
}

// ---------------- fp32 -> bf16 convert (vectorized) ----------------
__global__ void cvt_kernel(const float* __restrict__ src, bf16* __restrict__ dst, int n8) {
  int i = blockIdx.x * blockDim.x + threadIdx.x;
  const int stride = gridDim.x * blockDim.x;
  for (; i < n8; i += stride) {
    const float4 a = *((const float4*)src + (size_t)i * 2);
    const float4 b = *((const float4*)src + (size_t)i * 2 + 1);
    bf16x8 o;
    o[0] = (bf16)a.x; o[1] = (bf16)a.y; o[2] = (bf16)a.z; o[3] = (bf16)a.w;
    o[4] = (bf16)b.x; o[5] = (bf16)b.y; o[6] = (bf16)b.z; o[7] = (bf16)b.w;
    *(bf16x8*)(dst + (size_t)i * 8) = o;
  }
}

// ---------------- GEMM: C[m][n] = sum_k A[m][k]*B[n][k] + bias[n] ----------------
// m97 structure: 128x128 tile, BK=64, 4 waves (2x2 of 64x64), 16x16x32 bf16 MFMA,
// global_load_lds(16B) staging, 2 barriers per K-step.
template <int OUT_BF16>
__global__ __launch_bounds__(256, 2) void gemm_bt(
    const bf16* __restrict__ A, const bf16* __restrict__ Bm,
    const float* __restrict__ bias, void* __restrict__ Cout,
    int M, int N, int K)
{
  __shared__ __align__(16) bf16 As[128 * 64];
  __shared__ __align__(16) bf16 Bs[128 * 64];
  const int tid = threadIdx.x, wid = tid >> 6, lane = tid & 63;
  const int l15 = lane & 15, l16 = lane >> 4;
  const int m0 = blockIdx.y * 128, n0 = blockIdx.x * 128;
  const int wr = wid >> 1, wc = wid & 1;
  const f32x4 z4 = {0.f, 0.f, 0.f, 0.f};
  f32x4 acc[4][4];
#pragma unroll
  for (int a = 0; a < 4; ++a)
#pragma unroll
    for (int b = 0; b < 4; ++b) acc[a][b] = z4;

  for (int kt = 0; kt < K; kt += 64) {
#pragma unroll
    for (int it = 0; it < 4; ++it) {
      int slot = it * 256 + tid;
      int r = slot >> 3, g = slot & 7; // 8x 16B granules per 64-elem row
      async16(A  + (size_t)(m0 + r) * K + kt + g * 8, &As[slot * 8]);
      async16(Bm + (size_t)(n0 + r) * K + kt + g * 8, &Bs[slot * 8]);
    }
    __syncthreads(); // compiler drains vmcnt before s_barrier -> LDS ready
#pragma unroll
    for (int ks = 0; ks < 2; ++ks) {
      bf16x8 af[4], bfr[4];
#pragma unroll
      for (int mf = 0; mf < 4; ++mf)
        af[mf] = *(const bf16x8*)&As[(wr * 64 + mf * 16 + l15) * 64 + ks * 32 + l16 * 8];
#pragma unroll
      for (int nf = 0; nf < 4; ++nf)
        bfr[nf] = *(const bf16x8*)&Bs[(wc * 64 + nf * 16 + l15) * 64 + ks * 32 + l16 * 8];
#pragma unroll
      for (int mf = 0; mf < 4; ++mf)
#pragma unroll
        for (int nf = 0; nf < 4; ++nf)
          acc[mf][nf] = __builtin_amdgcn_mfma_f32_16x16x32_bf16(af[mf], bfr[nf], acc[mf][nf], 0, 0, 0);
    }
    __syncthreads();
  }
  // epilogue: D layout col = lane&15, row = (lane>>4)*4 + i  [guide m89/m91]
#pragma unroll
  for (int mf = 0; mf < 4; ++mf)
#pragma unroll
    for (int nf = 0; nf < 4; ++nf) {
      const int m = m0 + wr * 64 + mf * 16 + l16 * 4;
      const int n = n0 + wc * 64 + nf * 16 + l15;
      const float bv = bias[n];
#pragma unroll
      for (int i = 0; i < 4; ++i) {
        float v = acc[mf][nf][i] + bv;
        if (OUT_BF16) ((bf16*)Cout)[(size_t)(m + i) * N + n] = (bf16)v;
        else          ((float*)Cout)[(size_t)(m + i) * N + n] = v;
      }
    }
}

// ---------------- RoPE in place on [B,S,H,D] bf16 ----------------
__global__ void rope_kernel(bf16* __restrict__ x, const float* __restrict__ angles,
                            const int* __restrict__ flag, int force)
{
  if (!force && flag[0] == 0) return;
  const int t = threadIdx.x;
  const long R = (long)blockIdx.x * 64 + (t >> 2);  // head-row index in [0, B*S*H)
  const int d0 = (t & 3) * 16;
  const long s = (R / Hc) % Sc;
  bf16* rowp = x + R * Dc;
  bf16x8 lo0 = *(bf16x8*)(rowp + d0);
  bf16x8 lo1 = *(bf16x8*)(rowp + d0 + 8);
  bf16x8 hi0 = *(bf16x8*)(rowp + d0 + 64);
  bf16x8 hi1 = *(bf16x8*)(rowp + d0 + 72);
  const float* sp = angles + s * 64 + d0;            // angles[0] = sin
  const float* cp = angles + 131072 + s * 64 + d0;   // angles[1] = cos (S*D/2 = 131072)
  bf16x8 a0, a1, b0, b1;
#pragma unroll
  for (int j = 0; j < 8; ++j) {
    float c = cp[j], sn = sp[j];
    float x1 = (float)lo0[j], x2 = (float)hi0[j];
    a0[j] = (bf16)(x1 * c - x2 * sn);
    b0[j] = (bf16)(x1 * sn + x2 * c);
    float c1 = cp[j + 8], sn1 = sp[j + 8];
    float y1 = (float)lo1[j], y2 = (float)hi1[j];
    a1[j] = (bf16)(y1 * c1 - y2 * sn1);
    b1[j] = (bf16)(y1 * sn1 + y2 * c1);
  }
  *(bf16x8*)(rowp + d0)      = a0;
  *(bf16x8*)(rowp + d0 + 8)  = a1;
  *(bf16x8*)(rowp + d0 + 64) = b0;
  *(bf16x8*)(rowp + d0 + 72) = b1;
}

// ---------------- V transpose: v0 [B,S,H,D] -> Vt [BH][D][S] ----------------
__global__ void transpose_v(const bf16* __restrict__ v0, bf16* __restrict__ Vt)
{
  __shared__ __align__(16) bf16 T[64 * 128]; // [s_local][d], source-granule XOR swizzled
  const int t = threadIdx.x;
  const int bh = blockIdx.y, b = bh >> 4, h = bh & 15;
  const int s0 = blockIdx.x * 64;
#pragma unroll
  for (int it = 0; it < 4; ++it) {
    int slot = it * 256 + t;
    int r = slot >> 4, g = slot & 15; // 16 granules per 128-elem row
    async16(v0 + ((size_t)(b * Sc + s0 + r) * Hc + h) * Dc + ((g ^ (r & 15)) << 3),
            &T[slot * 8]);
  }
  __syncthreads();
  const int d = t >> 1, half = t & 1;
  bf16x8 pk[4];
#pragma unroll
  for (int j = 0; j < 32; ++j) {
    int sl = half * 32 + j;
    pk[j >> 3][j & 7] = T[sl * 128 + (((d >> 3) ^ (sl & 15)) << 3) + (d & 7)];
  }
  bf16* op = Vt + ((size_t)bh * Dc + d) * Sc + s0 + half * 32;
#pragma unroll
  for (int v = 0; v < 4; ++v) *(bf16x8*)(op + v * 8) = pk[v];
}

// ---------------- Flash attention ----------------
// Block: 4 waves x 32 q-rows = 128 q-rows of one (b,h). KVB=64, online softmax.
// K_lds [64][128], Vt_lds [128][64], P wave-private [32][64]; all XOR-granule swizzled.
__global__ __launch_bounds__(256, 2) void attn_kernel(
    const bf16* __restrict__ q0, const bf16* __restrict__ k0,
    const bf16* __restrict__ vt, const int* __restrict__ mask,
    const int* __restrict__ causal_p, bf16* __restrict__ attn_out)
{
  __shared__ __align__(16) bf16 Ks[64 * 128];
  __shared__ __align__(16) bf16 Vs[128 * 64];
  __shared__ __align__(16) bf16 Ps[4 * 32 * 64];
  __shared__ int maskS[64];

  const int tid = threadIdx.x, wid = tid >> 6, lane = tid & 63;
  const int l15 = lane & 15, l16 = lane >> 4;
  const int bh = blockIdx.y, b = bh >> 4, h = bh & 15;
  const int q_w = blockIdx.x * 128 + wid * 32;
  const int causal_f = causal_p[0];
  const float RSQ = 0.08838834764831845f; // 1/sqrt(128)

  // Q fragments resident in registers: A[m=q][k=d], lane m=l&15, k=(l>>4)*8+i
  bf16x8 qf[2][4];
#pragma unroll
  for (int mf = 0; mf < 2; ++mf)
#pragma unroll
    for (int ks = 0; ks < 4; ++ks)
      qf[mf][ks] = *(const bf16x8*)(q0 +
          ((size_t)(b * Sc + q_w + mf * 16 + l15) * Hc + h) * Dc + ks * 32 + l16 * 8);

  const f32x4 z4 = {0.f, 0.f, 0.f, 0.f};
  f32x4 o[2][8];
  float mrun[2][4], lrun[2][4];
#pragma unroll
  for (int mf = 0; mf < 2; ++mf) {
#pragma unroll
    for (int nf = 0; nf < 8; ++nf) o[mf][nf] = z4;
#pragma unroll
    for (int i = 0; i < 4; ++i) { mrun[mf][i] = -1e30f; lrun[mf][i] = 0.f; }
  }

  for (int kv0 = 0; kv0 < Sc; kv0 += 64) {
    __syncthreads(); // previous tile fully consumed
#pragma unroll
    for (int it = 0; it < 4; ++it) {
      int slot = it * 256 + tid;
      int r = slot >> 4, g = slot & 15;
      async16(k0 + ((size_t)(b * Sc + kv0 + r) * Hc + h) * Dc + ((g ^ (r & 7)) << 3),
              &Ks[slot * 8]);
    }
#pragma unroll
    for (int it = 0; it < 4; ++it) {
      int slot = it * 256 + tid;
      int r = slot >> 3, g = slot & 7;
      async16(vt + ((size_t)bh * Dc + r) * Sc + kv0 + ((g ^ (r & 7)) << 3),
              &Vs[slot * 8]);
    }
    if (tid < 64) maskS[tid] = mask[b * Sc + kv0 + tid];
    __syncthreads();

    // S = Q K^T : B[k=d][n=kv] read from Ks[kv][d] (swizzled)
    f32x4 sa[2][4];
#pragma unroll
    for (int mf = 0; mf < 2; ++mf)
#pragma unroll
      for (int nf = 0; nf < 4; ++nf) sa[mf][nf] = z4;
#pragma unroll
    for (int ks = 0; ks < 4; ++ks) {
      bf16x8 kb[4];
#pragma unroll
      for (int nf = 0; nf < 4; ++nf) {
        int row = nf * 16 + l15;
        kb[nf] = *(const bf16x8*)&Ks[row * 128 + (((ks * 4 + l16) ^ (row & 7)) << 3)];
      }
#pragma unroll
      for (int mf = 0; mf < 2; ++mf)
#pragma unroll
        for (int nf = 0; nf < 4; ++nf)
          sa[mf][nf] = __builtin_amdgcn_mfma_f32_16x16x32_bf16(qf[mf][ks], kb[nf], sa[mf][nf], 0, 0, 0);
    }

    // scale + mask (+ optional causal)
    float p[2][4][4];
#pragma unroll
    for (int mf = 0; mf < 2; ++mf)
#pragma unroll
      for (int nf = 0; nf < 4; ++nf) {
        const int kvl = nf * 16 + l15;
        const bool mok = (maskS[kvl] != 0);
#pragma unroll
        for (int i = 0; i < 4; ++i) {
          float s = sa[mf][nf][i] * RSQ;
          if (!mok) s = -1e30f;
          if (causal_f && (kv0 + kvl) > (q_w + mf * 16 + l16 * 4 + i)) s = -1e30f;
          p[mf][nf][i] = s;
        }
      }
    // online softmax: rows live in the 16-lane group (l&15 spans kv)
#pragma unroll
    for (int mf = 0; mf < 2; ++mf)
#pragma unroll
      for (int i = 0; i < 4; ++i) {
        float vm = fmaxf(fmaxf(p[mf][0][i], p[mf][1][i]), fmaxf(p[mf][2][i], p[mf][3][i]));
#pragma unroll
        for (int off = 1; off < 16; off <<= 1) vm = fmaxf(vm, __shfl_xor(vm, off));
        const float mnew = fmaxf(mrun[mf][i], vm);
        const float alpha = __expf(mrun[mf][i] - mnew);
        mrun[mf][i] = mnew;
        float rs = 0.f;
#pragma unroll
        for (int nf = 0; nf < 4; ++nf) {
          float e = __expf(p[mf][nf][i] - mnew);
          p[mf][nf][i] = e; rs += e;
        }
#pragma unroll
        for (int off = 1; off < 16; off <<= 1) rs += __shfl_xor(rs, off);
        lrun[mf][i] = lrun[mf][i] * alpha + rs;
#pragma unroll
        for (int nfd = 0; nfd < 8; ++nfd) o[mf][nfd][i] *= alpha;
      }
    // P -> wave-private LDS (A-operand layout, swizzled), then PV
#pragma unroll
    for (int mf = 0; mf < 2; ++mf)
#pragma unroll
      for (int nf = 0; nf < 4; ++nf)
#pragma unroll
        for (int i = 0; i < 4; ++i) {
          const int ql = mf * 16 + l16 * 4 + i;
          const int kvl = nf * 16 + l15;
          Ps[wid * 2048 + ql * 64 + ((((kvl >> 3) ^ (ql & 7))) << 3) + (kvl & 7)] =
              (bf16)p[mf][nf][i];
        }
#pragma unroll
    for (int ks2 = 0; ks2 < 2; ++ks2) {
      bf16x8 pa[2];
#pragma unroll
      for (int mf = 0; mf < 2; ++mf) {
        const int ql = mf * 16 + l15;
        pa[mf] = *(const bf16x8*)&Ps[wid * 2048 + ql * 64 + (((ks2 * 4 + l16) ^ (ql & 7)) << 3)];
      }
#pragma unroll
      for (int nfd = 0; nfd < 8; ++nfd) {
        const int dr = nfd * 16 + l15;
        bf16x8 vb = *(const bf16x8*)&Vs[dr * 64 + (((ks2 * 4 + l16) ^ (dr & 7)) << 3)];
#pragma unroll
        for (int mf = 0; mf < 2; ++mf)
          o[mf][nfd] = __builtin_amdgcn_mfma_f32_16x16x32_bf16(pa[mf], vb, o[mf][nfd], 0, 0, 0);
      }
    }
  }

  // epilogue: O / rowsum -> attn16 [B,S,H,D]
#pragma unroll
  for (int mf = 0; mf < 2; ++mf)
#pragma unroll
    for (int nfd = 0; nfd < 8; ++nfd)
#pragma unroll
      for (int i = 0; i < 4; ++i) {
        const int qr = q_w + mf * 16 + l16 * 4 + i;
        const int dcol = nfd * 16 + l15;
        attn_out[((size_t)(b * Sc + qr) * Hc + h) * Dc + dcol] =
            (bf16)(o[mf][nfd][i] / lrun[mf][i]);
      }
}

// ---------------- host ----------------
extern "C" void kernel_launch(void* const* d_in, const int* in_sizes, int n_in,
                              void* d_out, int out_size, void* d_ws, size_t ws_size,
                              hipStream_t stream)
{
  const float* x_q    = (const float*)d_in[0];
  const float* x_kv   = (const float*)d_in[1];
  const float* Wq     = (const float*)d_in[2];
  const float* bq     = (const float*)d_in[3];
  const float* Wk     = (const float*)d_in[4];
  const float* bk     = (const float*)d_in[5];
  const float* Wv     = (const float*)d_in[6];
  const float* bv     = (const float*)d_in[7];
  const float* Wo     = (const float*)d_in[8];
  const float* bo     = (const float*)d_in[9];
  const float* angles = (const float*)d_in[10];
  const int*   amask  = (const int*)d_in[11];
  const int*   causal = (const int*)d_in[12];
  const int*   k_rope = (const int*)d_in[13];
  float* out = (float*)d_out;

  char* ws = (char*)d_ws;
  const size_t MB32 = (size_t)33554432;
  bf16* xq16  = (bf16*)(ws);
  bf16* xkv16 = (bf16*)(ws + MB32);
  bf16* wq16  = (bf16*)(ws + 2 * MB32);
  bf16* wk16  = wq16 + 4194304;
  bf16* wv16  = wk16 + 4194304;
  bf16* wo16  = wv16 + 4194304;
  bf16* q0    = (bf16*)(ws + 3 * MB32);
  bf16* k0    = (bf16*)(ws + 4 * MB32);
  bf16* v0    = (bf16*)(ws + 5 * MB32);
  bf16* Vt     = xq16;   // xq16 dead after q-projection
  bf16* attn16 = xkv16;  // xkv16 dead after k/v-projections

  cvt_kernel<<<2048, 256, 0, stream>>>(x_q,  xq16,  Mc * Ec / 8);
  cvt_kernel<<<2048, 256, 0, stream>>>(x_kv, xkv16, Mc * Ec / 8);
  cvt_kernel<<<2048, 256, 0, stream>>>(Wq, wq16, Ec * Ec / 8);
  cvt_kernel<<<2048, 256, 0, stream>>>(Wk, wk16, Ec * Ec / 8);
  cvt_kernel<<<2048, 256, 0, stream>>>(Wv, wv16, Ec * Ec / 8);
  cvt_kernel<<<2048, 256, 0, stream>>>(Wo, wo16, Ec * Ec / 8);

  dim3 gg(Ec / 128, Mc / 128); // (16, 64)
  gemm_bt<1><<<gg, 256, 0, stream>>>(xq16,  wq16, bq, q0, Mc, Ec, Ec);
  gemm_bt<1><<<gg, 256, 0, stream>>>(xkv16, wk16, bk, k0, Mc, Ec, Ec);
  gemm_bt<1><<<gg, 256, 0, stream>>>(xkv16, wv16, bv, v0, Mc, Ec, Ec);

  rope_kernel<<<2048, 256, 0, stream>>>(q0, angles, k_rope, 1);
  rope_kernel<<<2048, 256, 0, stream>>>(k0, angles, k_rope, 0);
  transpose_v<<<dim3(Sc / 64, Bc * Hc), 256, 0, stream>>>(v0, Vt);

  attn_kernel<<<dim3(Sc / 128, Bc * Hc), 256, 0, stream>>>(q0, k0, Vt, amask, causal, attn16);

  gemm_bt<0><<<gg, 256, 0, stream>>>(attn16, wo16, bo, out, Mc, Ec, Ec);
}

// Round 2
// 772.525 us; speedup vs baseline: 1.0426x; 1.0426x over previous
//
#include <hip/hip_runtime.h>
#include <hip/hip_bf16.h>

// Fused MHA+RoPE pipeline for MI355X (gfx950), bf16 MFMA throughout.
// B=4, S=2048, E=2048, H=16, D=128, M=B*S=8192.
//
// ws layout (192 MB):
//   [0,32M)    xq16  -> later reused as Vt [BH][D][S]
//   [32,64M)   xkv16 -> later reused as attn16 [M][E]
//   [64,96M)   wq16,wk16,wv16,wo16 (8MB each)
//   [96,128M)  q0 [B,S,H,D] bf16 (roped in place)
//   [128,160M) k0
//   [160,192M) v0

typedef __bf16 bf16;
typedef __bf16 bf16x8 __attribute__((ext_vector_type(8)));
typedef __bf16 bf16x4 __attribute__((ext_vector_type(4)));
typedef __bf16 bf16x2 __attribute__((ext_vector_type(2)));
typedef float  f32x4  __attribute__((ext_vector_type(4)));
typedef float  f32x16 __attribute__((ext_vector_type(16)));

constexpr int Bc = 4, Sc = 2048, Ec = 2048, Hc = 16, Dc = 128;
constexpr int Mc = Bc * Sc; // 8192

__device__ __forceinline__ void async16(const void* g, void* l) {
  __builtin_amdgcn_global_load_lds(
      (const __attribute__((address_space(1))) void*)g,
      (__attribute__((address_space(3))) void*)l, 16, 0, 0);
}

__device__ __forceinline__ unsigned int pkbf(float a, float b) {
  union { bf16x2 v; unsigned int u; } c;
  c.v[0] = (bf16)a; c.v[1] = (bf16)b;
  return c.u;
}

// ---------------- fp32 -> bf16 convert (vectorized) ----------------
__global__ void cvt_kernel(const float* __restrict__ src, bf16* __restrict__ dst, int n8) {
  int i = blockIdx.x * blockDim.x + threadIdx.x;
  const int stride = gridDim.x * blockDim.x;
  for (; i < n8; i += stride) {
    const float4 a = *((const float4*)src + (size_t)i * 2);
    const float4 b = *((const float4*)src + (size_t)i * 2 + 1);
    bf16x8 o;
    o[0] = (bf16)a.x; o[1] = (bf16)a.y; o[2] = (bf16)a.z; o[3] = (bf16)a.w;
    o[4] = (bf16)b.x; o[5] = (bf16)b.y; o[6] = (bf16)b.z; o[7] = (bf16)b.w;
    *(bf16x8*)(dst + (size_t)i * 8) = o;
  }
}

// ---------------- GEMM: C[m][n] = sum_k A[m][k]*B[n][k] + bias[n] ----------------
template <int OUT_BF16>
__global__ __launch_bounds__(256, 2) void gemm_bt(
    const bf16* __restrict__ A, const bf16* __restrict__ Bm,
    const float* __restrict__ bias, void* __restrict__ Cout,
    int M, int N, int K)
{
  __shared__ __align__(16) bf16 As[128 * 64];
  __shared__ __align__(16) bf16 Bs[128 * 64];
  const int tid = threadIdx.x, wid = tid >> 6, lane = tid & 63;
  const int l15 = lane & 15, l16 = lane >> 4;
  const int m0 = blockIdx.y * 128, n0 = blockIdx.x * 128;
  const int wr = wid >> 1, wc = wid & 1;
  const f32x4 z4 = {0.f, 0.f, 0.f, 0.f};
  f32x4 acc[4][4];
#pragma unroll
  for (int a = 0; a < 4; ++a)
#pragma unroll
    for (int b = 0; b < 4; ++b) acc[a][b] = z4;

  for (int kt = 0; kt < K; kt += 64) {
#pragma unroll
    for (int it = 0; it < 4; ++it) {
      int slot = it * 256 + tid;
      int r = slot >> 3, g = slot & 7;
      async16(A  + (size_t)(m0 + r) * K + kt + g * 8, &As[slot * 8]);
      async16(Bm + (size_t)(n0 + r) * K + kt + g * 8, &Bs[slot * 8]);
    }
    __syncthreads();
#pragma unroll
    for (int ks = 0; ks < 2; ++ks) {
      bf16x8 af[4], bfr[4];
#pragma unroll
      for (int mf = 0; mf < 4; ++mf)
        af[mf] = *(const bf16x8*)&As[(wr * 64 + mf * 16 + l15) * 64 + ks * 32 + l16 * 8];
#pragma unroll
      for (int nf = 0; nf < 4; ++nf)
        bfr[nf] = *(const bf16x8*)&Bs[(wc * 64 + nf * 16 + l15) * 64 + ks * 32 + l16 * 8];
#pragma unroll
      for (int mf = 0; mf < 4; ++mf)
#pragma unroll
        for (int nf = 0; nf < 4; ++nf)
          acc[mf][nf] = __builtin_amdgcn_mfma_f32_16x16x32_bf16(af[mf], bfr[nf], acc[mf][nf], 0, 0, 0);
    }
    __syncthreads();
  }
#pragma unroll
  for (int mf = 0; mf < 4; ++mf)
#pragma unroll
    for (int nf = 0; nf < 4; ++nf) {
      const int m = m0 + wr * 64 + mf * 16 + l16 * 4;
      const int n = n0 + wc * 64 + nf * 16 + l15;
      const float bv = bias[n];
#pragma unroll
      for (int i = 0; i < 4; ++i) {
        float v = acc[mf][nf][i] + bv;
        if (OUT_BF16) ((bf16*)Cout)[(size_t)(m + i) * N + n] = (bf16)v;
        else          ((float*)Cout)[(size_t)(m + i) * N + n] = v;
      }
    }
}

// ---------------- RoPE in place on [B,S,H,D] bf16 ----------------
__global__ void rope_kernel(bf16* __restrict__ x, const float* __restrict__ angles,
                            const int* __restrict__ flag, int force)
{
  if (!force && flag[0] == 0) return;
  const int t = threadIdx.x;
  const long R = (long)blockIdx.x * 64 + (t >> 2);
  const int d0 = (t & 3) * 16;
  const long s = (R / Hc) % Sc;
  bf16* rowp = x + R * Dc;
  bf16x8 lo0 = *(bf16x8*)(rowp + d0);
  bf16x8 lo1 = *(bf16x8*)(rowp + d0 + 8);
  bf16x8 hi0 = *(bf16x8*)(rowp + d0 + 64);
  bf16x8 hi1 = *(bf16x8*)(rowp + d0 + 72);
  const float* sp = angles + s * 64 + d0;
  const float* cp = angles + 131072 + s * 64 + d0;
  bf16x8 a0, a1, b0, b1;
#pragma unroll
  for (int j = 0; j < 8; ++j) {
    float c = cp[j], sn = sp[j];
    float x1 = (float)lo0[j], x2 = (float)hi0[j];
    a0[j] = (bf16)(x1 * c - x2 * sn);
    b0[j] = (bf16)(x1 * sn + x2 * c);
    float c1 = cp[j + 8], sn1 = sp[j + 8];
    float y1 = (float)lo1[j], y2 = (float)hi1[j];
    a1[j] = (bf16)(y1 * c1 - y2 * sn1);
    b1[j] = (bf16)(y1 * sn1 + y2 * c1);
  }
  *(bf16x8*)(rowp + d0)      = a0;
  *(bf16x8*)(rowp + d0 + 8)  = a1;
  *(bf16x8*)(rowp + d0 + 64) = b0;
  *(bf16x8*)(rowp + d0 + 72) = b1;
}

// ---------------- V transpose: v0 [B,S,H,D] -> Vt [BH][D][S] ----------------
__global__ void transpose_v(const bf16* __restrict__ v0, bf16* __restrict__ Vt)
{
  __shared__ __align__(16) bf16 T[64 * 128];
  const int t = threadIdx.x;
  const int bh = blockIdx.y, b = bh >> 4, h = bh & 15;
  const int s0 = blockIdx.x * 64;
#pragma unroll
  for (int it = 0; it < 4; ++it) {
    int slot = it * 256 + t;
    int r = slot >> 4, g = slot & 15;
    async16(v0 + ((size_t)(b * Sc + s0 + r) * Hc + h) * Dc + ((g ^ (r & 15)) << 3),
            &T[slot * 8]);
  }
  __syncthreads();
  const int d = t >> 1, half = t & 1;
  bf16x8 pk[4];
#pragma unroll
  for (int j = 0; j < 32; ++j) {
    int sl = half * 32 + j;
    pk[j >> 3][j & 7] = T[sl * 128 + (((d >> 3) ^ (sl & 15)) << 3) + (d & 7)];
  }
  bf16* op = Vt + ((size_t)bh * Dc + d) * Sc + s0 + half * 32;
#pragma unroll
  for (int v = 0; v < 4; ++v) *(bf16x8*)(op + v * 8) = pk[v];
}

// ---------------- Flash attention, 32x32 swapped-operand structure ----------------
// 4 waves x 32 q-rows = 128 q per block. KV tile = 64 (2 sub-blocks of 32).
// S^T = mfma32(K, Q): lane owns q=lane&31, P row-chunk in 16 regs.
// Softmax in exp2 domain, in-register; P -> PV B-frags via pkbf + permlane32_swap.
// O^T = mfma32(V^T, P). No LDS for P; Ks/Vs XOR-swizzled (source-pre-swizzle).
__global__ __launch_bounds__(256, 3) void attn_kernel(
    const bf16* __restrict__ q0, const bf16* __restrict__ k0,
    const bf16* __restrict__ vt, const int* __restrict__ mask,
    const int* __restrict__ causal_p, bf16* __restrict__ attn_out)
{
  __shared__ __align__(16) bf16 Ks[64 * 128]; // [kv][d], 16B granule g^(kv&15)
  __shared__ __align__(16) bf16 Vs[128 * 64]; // [d][kv], 16B granule g^(d&7)

  const int tid = threadIdx.x, wid = tid >> 6, lane = tid & 63;
  const int l31 = lane & 31, h = lane >> 5;
  const int bh = blockIdx.y, b = bh >> 4, hh = bh & 15;
  const int q_glob = blockIdx.x * 128 + wid * 32 + l31;
  const int causal_f = causal_p[0];
  const float SC = 0.08838834764831845f * 1.4426950408889634f; // 1/sqrt(D) * log2(e)
  const float NEG = -3.0e38f;

  // Q B-fragments: col=q=l31, k = dc*16 + h*8 + j
  bf16x8 qf[8];
#pragma unroll
  for (int dc = 0; dc < 8; ++dc)
    qf[dc] = *(const bf16x8*)(q0 + ((size_t)(b * Sc + q_glob) * Hc + hh) * Dc + dc * 16 + h * 8);

  f32x16 o[4];
#pragma unroll
  for (int db = 0; db < 4; ++db)
#pragma unroll
    for (int r = 0; r < 16; ++r) o[db][r] = 0.f;
  float mrun = NEG, lrun = 0.f;

  for (int kv0 = 0; kv0 < Sc; kv0 += 64) {
    __syncthreads();
    // stage K tile [64][128]
#pragma unroll
    for (int it = 0; it < 4; ++it) {
      int g = it * 256 + tid;
      int r = g >> 4, gp = g & 15;
      async16(k0 + ((size_t)(b * Sc + kv0 + r) * Hc + hh) * Dc + ((gp ^ (r & 15)) << 3),
              &Ks[g * 8]);
    }
    // stage V^T tile [128][64]
#pragma unroll
    for (int it = 0; it < 4; ++it) {
      int g = it * 256 + tid;
      int r = g >> 3, gp = g & 7;
      async16(vt + ((size_t)bh * Dc + r) * Sc + kv0 + ((gp ^ (r & 7)) << 3),
              &Vs[g * 8]);
    }
    const unsigned long long mbits = __ballot(mask[b * Sc + kv0 + lane] != 0);
    __syncthreads();

#pragma unroll
    for (int kvb = 0; kvb < 2; ++kvb) {
      // ---- S^T = K * Q (A = K rows=kv, B = Q cols=q) ----
      f32x16 s;
#pragma unroll
      for (int r = 0; r < 16; ++r) s[r] = 0.f;
#pragma unroll
      for (int dc = 0; dc < 8; ++dc) {
        bf16x8 kf = *(const bf16x8*)&Ks[(kvb * 32 + l31) * 128 +
                                        (((dc * 2 + h) ^ (l31 & 15)) << 3)];
        s = __builtin_amdgcn_mfma_f32_32x32x16_bf16(kf, qf[dc], s, 0, 0, 0);
      }
      // scale into log2 domain
#pragma unroll
      for (int r = 0; r < 16; ++r) s[r] *= SC;
      // mask (fast path: all ones -> skip entirely, wave-uniform)
      if (mbits != ~0ull) {
#pragma unroll
        for (int r = 0; r < 16; ++r) {
          int off = kvb * 32 + (r & 3) + 8 * (r >> 2) + 4 * h;
          if (!((mbits >> off) & 1)) s[r] = NEG;
        }
      }
      if (causal_f) {
#pragma unroll
        for (int r = 0; r < 16; ++r) {
          int kvg = kv0 + kvb * 32 + (r & 3) + 8 * (r >> 2) + 4 * h;
          if (kvg > q_glob) s[r] = NEG;
        }
      }
      // ---- online softmax (row q = l31, halves combined via shfl_xor 32) ----
      float tmax = s[0];
#pragma unroll
      for (int r = 1; r < 16; ++r) tmax = fmaxf(tmax, s[r]);
      tmax = fmaxf(tmax, __shfl_xor(tmax, 32));
      if (!__all(tmax <= mrun + 8.0f)) { // defer-max (T13), THR=8 in log2 dom.
        const float mnew = fmaxf(mrun, tmax);
        const float alpha = __builtin_amdgcn_exp2f(mrun - mnew);
#pragma unroll
        for (int db = 0; db < 4; ++db)
#pragma unroll
          for (int r = 0; r < 16; ++r) o[db][r] *= alpha;
        lrun *= alpha;
        mrun = mnew;
      }
      float rs = 0.f;
#pragma unroll
      for (int r = 0; r < 16; ++r) {
        s[r] = __builtin_amdgcn_exp2f(s[r] - mrun);
        rs += s[r];
      }
      rs += __shfl_xor(rs, 32);
      lrun += rs;
      // ---- P -> bf16 B-fragments via pack + permlane32_swap ----
      unsigned int dw0 = pkbf(s[0], s[1]),  dw1 = pkbf(s[2], s[3]);
      unsigned int dw2 = pkbf(s[4], s[5]),  dw3 = pkbf(s[6], s[7]);
      unsigned int dw4 = pkbf(s[8], s[9]),  dw5 = pkbf(s[10], s[11]);
      unsigned int dw6 = pkbf(s[12], s[13]), dw7 = pkbf(s[14], s[15]);
      asm volatile("v_permlane32_swap_b32 %0, %1" : "+v"(dw0), "+v"(dw2));
      asm volatile("v_permlane32_swap_b32 %0, %1" : "+v"(dw1), "+v"(dw3));
      asm volatile("v_permlane32_swap_b32 %0, %1" : "+v"(dw4), "+v"(dw6));
      asm volatile("v_permlane32_swap_b32 %0, %1" : "+v"(dw5), "+v"(dw7));
      union { unsigned int u[4]; bf16x8 v; } pf0, pf1;
      pf0.u[0] = dw0; pf0.u[1] = dw1; pf0.u[2] = dw2; pf0.u[3] = dw3;
      pf1.u[0] = dw4; pf1.u[1] = dw5; pf1.u[2] = dw6; pf1.u[3] = dw7;
      // ---- O^T += V^T * P  (A = V^T rows=d, B = P cols=q) ----
#pragma unroll
      for (int ksb = 0; ksb < 2; ++ksb) {
        const bf16x8 pf = ksb ? pf1.v : pf0.v;
#pragma unroll
        for (int db = 0; db < 4; ++db) {
          const int dr = db * 32 + l31;
          bf16x8 vb = *(const bf16x8*)&Vs[dr * 64 +
                          ((((kvb * 2 + ksb) * 2 + h) ^ (dr & 7)) << 3)];
          o[db] = __builtin_amdgcn_mfma_f32_32x32x16_bf16(vb, pf, o[db], 0, 0, 0);
        }
      }
    }
  }

  // epilogue: lane owns row q_glob, d = db*32 + 8*rq + 4*h + i
  const float inv = 1.0f / lrun;
  bf16* orow = attn_out + ((size_t)(b * Sc + q_glob) * Hc + hh) * Dc;
#pragma unroll
  for (int db = 0; db < 4; ++db)
#pragma unroll
    for (int rq = 0; rq < 4; ++rq) {
      bf16x4 st;
#pragma unroll
      for (int i = 0; i < 4; ++i) st[i] = (bf16)(o[db][rq * 4 + i] * inv);
      *(bf16x4*)(orow + db * 32 + rq * 8 + 4 * h) = st;
    }
}

// ---------------- host ----------------
extern "C" void kernel_launch(void* const* d_in, const int* in_sizes, int n_in,
                              void* d_out, int out_size, void* d_ws, size_t ws_size,
                              hipStream_t stream)
{
  const float* x_q    = (const float*)d_in[0];
  const float* x_kv   = (const float*)d_in[1];
  const float* Wq     = (const float*)d_in[2];
  const float* bq     = (const float*)d_in[3];
  const float* Wk     = (const float*)d_in[4];
  const float* bk     = (const float*)d_in[5];
  const float* Wv     = (const float*)d_in[6];
  const float* bv     = (const float*)d_in[7];
  const float* Wo     = (const float*)d_in[8];
  const float* bo     = (const float*)d_in[9];
  const float* angles = (const float*)d_in[10];
  const int*   amask  = (const int*)d_in[11];
  const int*   causal = (const int*)d_in[12];
  const int*   k_rope = (const int*)d_in[13];
  float* out = (float*)d_out;

  char* ws = (char*)d_ws;
  const size_t MB32 = (size_t)33554432;
  bf16* xq16  = (bf16*)(ws);
  bf16* xkv16 = (bf16*)(ws + MB32);
  bf16* wq16  = (bf16*)(ws + 2 * MB32);
  bf16* wk16  = wq16 + 4194304;
  bf16* wv16  = wk16 + 4194304;
  bf16* wo16  = wv16 + 4194304;
  bf16* q0    = (bf16*)(ws + 3 * MB32);
  bf16* k0    = (bf16*)(ws + 4 * MB32);
  bf16* v0    = (bf16*)(ws + 5 * MB32);
  bf16* Vt     = xq16;   // xq16 dead after q-projection
  bf16* attn16 = xkv16;  // xkv16 dead after k/v-projections

  cvt_kernel<<<2048, 256, 0, stream>>>(x_q,  xq16,  Mc * Ec / 8);
  cvt_kernel<<<2048, 256, 0, stream>>>(x_kv, xkv16, Mc * Ec / 8);
  cvt_kernel<<<2048, 256, 0, stream>>>(Wq, wq16, Ec * Ec / 8);
  cvt_kernel<<<2048, 256, 0, stream>>>(Wk, wk16, Ec * Ec / 8);
  cvt_kernel<<<2048, 256, 0, stream>>>(Wv, wv16, Ec * Ec / 8);
  cvt_kernel<<<2048, 256, 0, stream>>>(Wo, wo16, Ec * Ec / 8);

  dim3 gg(Ec / 128, Mc / 128);
  gemm_bt<1><<<gg, 256, 0, stream>>>(xq16,  wq16, bq, q0, Mc, Ec, Ec);
  gemm_bt<1><<<gg, 256, 0, stream>>>(xkv16, wk16, bk, k0, Mc, Ec, Ec);
  gemm_bt<1><<<gg, 256, 0, stream>>>(xkv16, wv16, bv, v0, Mc, Ec, Ec);

  rope_kernel<<<2048, 256, 0, stream>>>(q0, angles, k_rope, 1);
  rope_kernel<<<2048, 256, 0, stream>>>(k0, angles, k_rope, 0);
  transpose_v<<<dim3(Sc / 64, Bc * Hc), 256, 0, stream>>>(v0, Vt);

  attn_kernel<<<dim3(Sc / 128, Bc * Hc), 256, 0, stream>>>(q0, k0, Vt, amask, causal, attn16);

  gemm_bt<0><<<gg, 256, 0, stream>>>(attn16, wo16, bo, out, Mc, Ec, Ec);
}

// Round 3
// 545.355 us; speedup vs baseline: 1.4769x; 1.4166x over previous
//
#include <hip/hip_runtime.h>
#include <hip/hip_bf16.h>

// Fused MHA+RoPE pipeline for MI355X (gfx950), bf16 MFMA throughout.
// B=4, S=2048, E=2048, H=16, D=128, M=B*S=8192.
//
// ws layout (192 MB):
//   [0,32M)    xq16  -> later reused as Vt [BH][D][S]
//   [32,64M)   xkv16 -> later reused as attn16 [M][E]
//   [64,96M)   wq16,wk16,wv16,wo16 (8MB each)
//   [96,128M)  q0 [B,S,H,D] bf16 (roped in place)
//   [128,160M) k0
//   [160,192M) v0

typedef __bf16 bf16;
typedef __bf16 bf16x8 __attribute__((ext_vector_type(8)));
typedef __bf16 bf16x4 __attribute__((ext_vector_type(4)));
typedef __bf16 bf16x2 __attribute__((ext_vector_type(2)));
typedef float  f32x4  __attribute__((ext_vector_type(4)));
typedef float  f32x16 __attribute__((ext_vector_type(16)));

constexpr int Bc = 4, Sc = 2048, Ec = 2048, Hc = 16, Dc = 128;
constexpr int Mc = Bc * Sc; // 8192

__device__ __forceinline__ void async16(const void* g, void* l) {
  __builtin_amdgcn_global_load_lds(
      (const __attribute__((address_space(1))) void*)g,
      (__attribute__((address_space(3))) void*)l, 16, 0, 0);
}

__device__ __forceinline__ unsigned int pkbf(float a, float b) {
  union { bf16x2 v; unsigned int u; } c;
  c.v[0] = (bf16)a; c.v[1] = (bf16)b;
  return c.u;
}

// st_16x32 swizzle on a [R][32] bf16 tile (row stride 64B): byte ^= ((byte>>9)&1)<<5
__device__ __forceinline__ int swzb32(int r, int kb) {
  int b = r * 64 + kb;
  return b ^ (((b >> 9) & 1) << 5);
}

// ---------------- fp32 -> bf16 convert (vectorized) ----------------
__global__ void cvt_kernel(const float* __restrict__ src, bf16* __restrict__ dst, int n8) {
  int i = blockIdx.x * blockDim.x + threadIdx.x;
  const int stride = gridDim.x * blockDim.x;
  for (; i < n8; i += stride) {
    const float4 a = *((const float4*)src + (size_t)i * 2);
    const float4 b = *((const float4*)src + (size_t)i * 2 + 1);
    bf16x8 o;
    o[0] = (bf16)a.x; o[1] = (bf16)a.y; o[2] = (bf16)a.z; o[3] = (bf16)a.w;
    o[4] = (bf16)b.x; o[5] = (bf16)b.y; o[6] = (bf16)b.z; o[7] = (bf16)b.w;
    *(bf16x8*)(dst + (size_t)i * 8) = o;
  }
}

// ---------------- GEMM: C[m][n] = sum_k A[m][k]*B[n][k] + bias[n] ----------------
// 256x256 tile, BK=32, 8 waves (2Mx4N, per-wave 128x64), triple-buffered LDS ring
// (96KB) with prefetch distance 2, counted vmcnt(4) at tile boundaries, T2 st_16x32
// swizzle (inverse-swizzled global source + swizzled ds_read), T5 setprio.
// Ring safety: stages for tile t+2 (issued during tile t) write buf[(t+2)%3]; that
// buffer's reads were tile t-1's, complete at t-1's end barrier BEFORE tile t begins.
// The writes are waited by the vmcnt at end of tile t+1, before tile t+2's reads.
// Fixed shape: M=8192 (or any mult of 256), N=2048, K=2048; lda=ldb=2048.
template <int OUT_BF16>
__global__ __launch_bounds__(512, 2) void gemm8(
    const bf16* __restrict__ A, const bf16* __restrict__ Bm,
    const float* __restrict__ bias, void* __restrict__ Cout, int Mblocks)
{
  __shared__ __align__(16) bf16 lds[3 * 16384]; // 3 bufs x (A 16KB + B 16KB)
  const int tid = threadIdx.x;
  const int w = tid >> 6, lane = tid & 63;
  const int l15 = lane & 15, l16 = lane >> 4;
  const int wm = w >> 2, wn = w & 3;
  // XCD-aware swizzle (nwg = Mblocks*8, multiple of 8)
  const int id = blockIdx.x;
  const int nwg = Mblocks * 8, cpx = nwg >> 3;
  const int swz = (id & 7) * cpx + (id >> 3);
  const int by = swz >> 3, bx = swz & 7;
  const long m0 = (long)by * 256, n0 = (long)bx * 256;
  constexpr int NT = 64; // K/32

  auto stA = [&](int buf, long kt, int j) {
    int c = w * 128 + j * 64 + lane;              // LDS chunk 0..1023
    int cs = c ^ (((c >> 5) & 1) << 1);           // logical chunk (involution)
    async16(A + (m0 + (cs >> 2)) * 2048 + kt + (cs & 3) * 8,
            &lds[buf * 16384 + c * 8]);
  };
  auto stB = [&](int buf, long kt, int j) {
    int c = w * 128 + j * 64 + lane;
    int cs = c ^ (((c >> 5) & 1) << 1);
    async16(Bm + (n0 + (cs >> 2)) * 2048 + kt + (cs & 3) * 8,
            &lds[buf * 16384 + 8192 + c * 8]);
  };

  f32x4 acc[8][4];
#pragma unroll
  for (int a = 0; a < 8; ++a)
#pragma unroll
    for (int b = 0; b < 4; ++b) acc[a][b] = f32x4{0.f, 0.f, 0.f, 0.f};

  // prologue: stage tiles 0,1 fully; wait tile0 (counted), barrier.
  stA(0, 0, 0); stA(0, 0, 1); stB(0, 0, 0); stB(0, 0, 1);
  stA(1, 32, 0); stA(1, 32, 1); stB(1, 32, 0); stB(1, 32, 1);
  asm volatile("s_waitcnt vmcnt(4)" ::: "memory");
  __builtin_amdgcn_s_barrier();

  int cur = 0, nx = 2;
  for (int t = 0; t < NT; ++t) {
    const char* Ab = (const char*)&lds[cur * 16384];
    const char* Bb = Ab + 16384;
    const long ktn = (long)(t + 2) * 32;
    const bool pf = (t < NT - 2);

    // ---- phase 0: A frags (shared by both phases) + B cols 0..31 ----
    bf16x8 af[8], bf0[2];
#pragma unroll
    for (int mf = 0; mf < 8; ++mf)
      af[mf] = *(const bf16x8*)(Ab + swzb32(wm * 128 + mf * 16 + l15, l16 * 16));
#pragma unroll
    for (int nf = 0; nf < 2; ++nf)
      bf0[nf] = *(const bf16x8*)(Bb + swzb32(wn * 64 + nf * 16 + l15, l16 * 16));
    if (pf) { stA(nx, ktn, 0); stA(nx, ktn, 1); }
    asm volatile("" ::: "memory");
    __builtin_amdgcn_s_barrier();
    __builtin_amdgcn_s_setprio(1);
#pragma unroll
    for (int mf = 0; mf < 8; ++mf)
#pragma unroll
      for (int nf = 0; nf < 2; ++nf)
        acc[mf][nf] = __builtin_amdgcn_mfma_f32_16x16x32_bf16(af[mf], bf0[nf], acc[mf][nf], 0, 0, 0);
    __builtin_amdgcn_s_setprio(0);
    __builtin_amdgcn_s_barrier();

    // ---- phase 1: B cols 32..63 (reuse af) ----
    bf16x8 bf1[2];
#pragma unroll
    for (int nf = 0; nf < 2; ++nf)
      bf1[nf] = *(const bf16x8*)(Bb + swzb32(wn * 64 + (2 + nf) * 16 + l15, l16 * 16));
    if (pf) { stB(nx, ktn, 0); stB(nx, ktn, 1); }
    asm volatile("" ::: "memory");
    __builtin_amdgcn_s_barrier();
    __builtin_amdgcn_s_setprio(1);
#pragma unroll
    for (int mf = 0; mf < 8; ++mf)
#pragma unroll
      for (int nf = 0; nf < 2; ++nf)
        acc[mf][2 + nf] = __builtin_amdgcn_mfma_f32_16x16x32_bf16(af[mf], bf1[nf], acc[mf][2 + nf], 0, 0, 0);
    __builtin_amdgcn_s_setprio(0);
    if (t < NT - 2)       { asm volatile("s_waitcnt vmcnt(4)" ::: "memory"); }
    else if (t == NT - 2) { asm volatile("s_waitcnt vmcnt(0)" ::: "memory"); }
    __builtin_amdgcn_s_barrier();
    cur = (cur == 2) ? 0 : cur + 1;
    nx  = (nx  == 2) ? 0 : nx  + 1;
  }

  // epilogue: D layout col = lane&15, row = (lane>>4)*4 + i
#pragma unroll
  for (int mf = 0; mf < 8; ++mf)
#pragma unroll
    for (int nf = 0; nf < 4; ++nf) {
      const long m = m0 + wm * 128 + mf * 16 + l16 * 4;
      const long n = n0 + wn * 64 + nf * 16 + l15;
      const float bv = bias[n];
#pragma unroll
      for (int i = 0; i < 4; ++i) {
        float v = acc[mf][nf][i] + bv;
        if (OUT_BF16) ((bf16*)Cout)[(m + i) * 2048 + n] = (bf16)v;
        else          ((float*)Cout)[(m + i) * 2048 + n] = v;
      }
    }
}

// ---------------- RoPE in place on [B,S,H,D] bf16 ----------------
__global__ void rope_kernel(bf16* __restrict__ x, const float* __restrict__ angles,
                            const int* __restrict__ flag, int force)
{
  if (!force && flag[0] == 0) return;
  const int t = threadIdx.x;
  const long R = (long)blockIdx.x * 64 + (t >> 2);
  const int d0 = (t & 3) * 16;
  const long s = (R / Hc) % Sc;
  bf16* rowp = x + R * Dc;
  bf16x8 lo0 = *(bf16x8*)(rowp + d0);
  bf16x8 lo1 = *(bf16x8*)(rowp + d0 + 8);
  bf16x8 hi0 = *(bf16x8*)(rowp + d0 + 64);
  bf16x8 hi1 = *(bf16x8*)(rowp + d0 + 72);
  const float* sp = angles + s * 64 + d0;
  const float* cp = angles + 131072 + s * 64 + d0;
  bf16x8 a0, a1, b0, b1;
#pragma unroll
  for (int j = 0; j < 8; ++j) {
    float c = cp[j], sn = sp[j];
    float x1 = (float)lo0[j], x2 = (float)hi0[j];
    a0[j] = (bf16)(x1 * c - x2 * sn);
    b0[j] = (bf16)(x1 * sn + x2 * c);
    float c1 = cp[j + 8], sn1 = sp[j + 8];
    float y1 = (float)lo1[j], y2 = (float)hi1[j];
    a1[j] = (bf16)(y1 * c1 - y2 * sn1);
    b1[j] = (bf16)(y1 * sn1 + y2 * c1);
  }
  *(bf16x8*)(rowp + d0)      = a0;
  *(bf16x8*)(rowp + d0 + 8)  = a1;
  *(bf16x8*)(rowp + d0 + 64) = b0;
  *(bf16x8*)(rowp + d0 + 72) = b1;
}

// ---------------- V transpose: v0 [B,S,H,D] -> Vt [BH][D][S] ----------------
__global__ void transpose_v(const bf16* __restrict__ v0, bf16* __restrict__ Vt)
{
  __shared__ __align__(16) bf16 T[64 * 128];
  const int t = threadIdx.x;
  const int bh = blockIdx.y, b = bh >> 4, h = bh & 15;
  const int s0 = blockIdx.x * 64;
#pragma unroll
  for (int it = 0; it < 4; ++it) {
    int slot = it * 256 + t;
    int r = slot >> 4, g = slot & 15;
    async16(v0 + ((size_t)(b * Sc + s0 + r) * Hc + h) * Dc + ((g ^ (r & 15)) << 3),
            &T[slot * 8]);
  }
  __syncthreads();
  const int d = t >> 1, half = t & 1;
  bf16x8 pk[4];
#pragma unroll
  for (int j = 0; j < 32; ++j) {
    int sl = half * 32 + j;
    pk[j >> 3][j & 7] = T[sl * 128 + (((d >> 3) ^ (sl & 15)) << 3) + (d & 7)];
  }
  bf16* op = Vt + ((size_t)bh * Dc + d) * Sc + s0 + half * 32;
#pragma unroll
  for (int v = 0; v < 4; ++v) *(bf16x8*)(op + v * 8) = pk[v];
}

// ---------------- Flash attention, 32x32 swapped-operand + 2-phase dbuf ----------------
// 4 waves x 32 q-rows. KV tile 64. Double-buffered K/V staging (T3-minimum recipe):
// issue STAGE(next) BEFORE compute(cur); one vmcnt(0)+barrier per tile (drain is free:
// the loads had the whole compute phase to land). T5 setprio around MFMA clusters.
__global__ __launch_bounds__(256, 2) void attn_kernel(
    const bf16* __restrict__ q0, const bf16* __restrict__ k0,
    const bf16* __restrict__ vt, const int* __restrict__ mask,
    const int* __restrict__ causal_p, bf16* __restrict__ attn_out)
{
  __shared__ __align__(16) bf16 Ks[2][64 * 128]; // [kv][d], 16B granule g^(kv&15)
  __shared__ __align__(16) bf16 Vs[2][128 * 64]; // [d][kv], 16B granule g^(d&7)

  const int tid = threadIdx.x, wid = tid >> 6, lane = tid & 63;
  const int l31 = lane & 31, h = lane >> 5;
  // XCD swizzle: 1024 blocks; all 16 q-blocks of one (b,h) land on the same XCD.
  const int id = blockIdx.x;
  const int swz = (id & 7) * 128 + (id >> 3);
  const int bh = swz >> 4, qb = swz & 15;
  const int b = bh >> 4, hh = bh & 15;
  const int q_glob = qb * 128 + wid * 32 + l31;
  const int causal_f = causal_p[0];
  const float SC = 0.08838834764831845f * 1.4426950408889634f; // 1/sqrt(D) * log2(e)
  const float NEG = -3.0e38f;

  auto stageKV = [&](int kv0s, int bufs) {
#pragma unroll
    for (int it = 0; it < 4; ++it) {
      int g = it * 256 + tid;
      int r = g >> 4, gp = g & 15;
      async16(k0 + ((size_t)(b * Sc + kv0s + r) * Hc + hh) * Dc + ((gp ^ (r & 15)) << 3),
              &Ks[bufs][g * 8]);
    }
#pragma unroll
    for (int it = 0; it < 4; ++it) {
      int g = it * 256 + tid;
      int r = g >> 3, gp = g & 7;
      async16(vt + ((size_t)bh * Dc + r) * Sc + kv0s + ((gp ^ (r & 7)) << 3),
              &Vs[bufs][g * 8]);
    }
  };

  // Q B-fragments: col=q=l31, k = dc*16 + h*8 + j
  bf16x8 qf[8];
#pragma unroll
  for (int dc = 0; dc < 8; ++dc)
    qf[dc] = *(const bf16x8*)(q0 + ((size_t)(b * Sc + q_glob) * Hc + hh) * Dc + dc * 16 + h * 8);

  f32x16 o[4];
#pragma unroll
  for (int db = 0; db < 4; ++db)
#pragma unroll
    for (int r = 0; r < 16; ++r) o[db][r] = 0.f;
  float mrun = NEG, lrun = 0.f;

  stageKV(0, 0);
  asm volatile("s_waitcnt vmcnt(0)" ::: "memory");
  __builtin_amdgcn_s_barrier();
  int cur = 0;

  for (int kv0 = 0; kv0 < Sc; kv0 += 64) {
    if (kv0 + 64 < Sc) stageKV(kv0 + 64, cur ^ 1); // issue early, lands during compute
    const unsigned long long mbits = __ballot(mask[b * Sc + kv0 + lane] != 0);

#pragma unroll
    for (int kvb = 0; kvb < 2; ++kvb) {
      // ---- S^T = K * Q ----
      f32x16 s;
#pragma unroll
      for (int r = 0; r < 16; ++r) s[r] = 0.f;
      __builtin_amdgcn_s_setprio(1);
#pragma unroll
      for (int dc = 0; dc < 8; ++dc) {
        bf16x8 kf = *(const bf16x8*)&Ks[cur][(kvb * 32 + l31) * 128 +
                                           (((dc * 2 + h) ^ (l31 & 15)) << 3)];
        s = __builtin_amdgcn_mfma_f32_32x32x16_bf16(kf, qf[dc], s, 0, 0, 0);
      }
      __builtin_amdgcn_s_setprio(0);
#pragma unroll
      for (int r = 0; r < 16; ++r) s[r] *= SC;
      if (mbits != ~0ull) {
#pragma unroll
        for (int r = 0; r < 16; ++r) {
          int off = kvb * 32 + (r & 3) + 8 * (r >> 2) + 4 * h;
          if (!((mbits >> off) & 1)) s[r] = NEG;
        }
      }
      if (causal_f) {
#pragma unroll
        for (int r = 0; r < 16; ++r) {
          int kvg = kv0 + kvb * 32 + (r & 3) + 8 * (r >> 2) + 4 * h;
          if (kvg > q_glob) s[r] = NEG;
        }
      }
      // ---- online softmax (row q = l31; halves via shfl_xor 32) ----
      float tmax = s[0];
#pragma unroll
      for (int r = 1; r < 16; ++r) tmax = fmaxf(tmax, s[r]);
      tmax = fmaxf(tmax, __shfl_xor(tmax, 32));
      if (!__all(tmax <= mrun + 8.0f)) { // defer-max (T13)
        const float mnew = fmaxf(mrun, tmax);
        const float alpha = __builtin_amdgcn_exp2f(mrun - mnew);
#pragma unroll
        for (int db = 0; db < 4; ++db)
#pragma unroll
          for (int r = 0; r < 16; ++r) o[db][r] *= alpha;
        lrun *= alpha;
        mrun = mnew;
      }
      float rs = 0.f;
#pragma unroll
      for (int r = 0; r < 16; ++r) {
        s[r] = __builtin_amdgcn_exp2f(s[r] - mrun);
        rs += s[r];
      }
      rs += __shfl_xor(rs, 32);
      lrun += rs;
      // ---- P -> bf16 B-fragments via pack + permlane32_swap ----
      unsigned int dw0 = pkbf(s[0], s[1]),   dw1 = pkbf(s[2], s[3]);
      unsigned int dw2 = pkbf(s[4], s[5]),   dw3 = pkbf(s[6], s[7]);
      unsigned int dw4 = pkbf(s[8], s[9]),   dw5 = pkbf(s[10], s[11]);
      unsigned int dw6 = pkbf(s[12], s[13]), dw7 = pkbf(s[14], s[15]);
      asm volatile("v_permlane32_swap_b32 %0, %1" : "+v"(dw0), "+v"(dw2));
      asm volatile("v_permlane32_swap_b32 %0, %1" : "+v"(dw1), "+v"(dw3));
      asm volatile("v_permlane32_swap_b32 %0, %1" : "+v"(dw4), "+v"(dw6));
      asm volatile("v_permlane32_swap_b32 %0, %1" : "+v"(dw5), "+v"(dw7));
      union { unsigned int u[4]; bf16x8 v; } pf0, pf1;
      pf0.u[0] = dw0; pf0.u[1] = dw1; pf0.u[2] = dw2; pf0.u[3] = dw3;
      pf1.u[0] = dw4; pf1.u[1] = dw5; pf1.u[2] = dw6; pf1.u[3] = dw7;
      // ---- O^T += V^T * P ----
      __builtin_amdgcn_s_setprio(1);
#pragma unroll
      for (int ksb = 0; ksb < 2; ++ksb) {
        const bf16x8 pfv = ksb ? pf1.v : pf0.v;
#pragma unroll
        for (int db = 0; db < 4; ++db) {
          const int dr = db * 32 + l31;
          bf16x8 vb = *(const bf16x8*)&Vs[cur][dr * 64 +
                          ((((kvb * 2 + ksb) * 2 + h) ^ (dr & 7)) << 3)];
          o[db] = __builtin_amdgcn_mfma_f32_32x32x16_bf16(vb, pfv, o[db], 0, 0, 0);
        }
      }
      __builtin_amdgcn_s_setprio(0);
    }
    asm volatile("s_waitcnt vmcnt(0)" ::: "memory"); // next tile staged (drain ~free)
    __builtin_amdgcn_s_barrier();
    cur ^= 1;
  }

  // epilogue: lane owns row q_glob, d = db*32 + 8*rq + 4*h + i
  const float inv = 1.0f / lrun;
  bf16* orow = attn_out + ((size_t)(b * Sc + q_glob) * Hc + hh) * Dc;
#pragma unroll
  for (int db = 0; db < 4; ++db)
#pragma unroll
    for (int rq = 0; rq < 4; ++rq) {
      bf16x4 st;
#pragma unroll
      for (int i = 0; i < 4; ++i) st[i] = (bf16)(o[db][rq * 4 + i] * inv);
      *(bf16x4*)(orow + db * 32 + rq * 8 + 4 * h) = st;
    }
}

// ---------------- host ----------------
extern "C" void kernel_launch(void* const* d_in, const int* in_sizes, int n_in,
                              void* d_out, int out_size, void* d_ws, size_t ws_size,
                              hipStream_t stream)
{
  const float* x_q    = (const float*)d_in[0];
  const float* x_kv   = (const float*)d_in[1];
  const float* Wq     = (const float*)d_in[2];
  const float* bq     = (const float*)d_in[3];
  const float* Wk     = (const float*)d_in[4];
  const float* bk     = (const float*)d_in[5];
  const float* Wv     = (const float*)d_in[6];
  const float* bv     = (const float*)d_in[7];
  const float* Wo     = (const float*)d_in[8];
  const float* bo     = (const float*)d_in[9];
  const float* angles = (const float*)d_in[10];
  const int*   amask  = (const int*)d_in[11];
  const int*   causal = (const int*)d_in[12];
  const int*   k_rope = (const int*)d_in[13];
  float* out = (float*)d_out;

  char* ws = (char*)d_ws;
  const size_t MB32 = (size_t)33554432;
  bf16* xq16  = (bf16*)(ws);
  bf16* xkv16 = (bf16*)(ws + MB32);
  bf16* wq16  = (bf16*)(ws + 2 * MB32);
  bf16* wk16  = wq16 + 4194304;
  bf16* wv16  = wk16 + 4194304;
  bf16* wo16  = wv16 + 4194304;
  bf16* q0    = (bf16*)(ws + 3 * MB32);
  bf16* k0    = (bf16*)(ws + 4 * MB32);
  bf16* v0    = (bf16*)(ws + 5 * MB32);
  bf16* Vt     = xq16;   // xq16 dead after q-projection
  bf16* attn16 = xkv16;  // xkv16 dead after k/v-projections

  cvt_kernel<<<2048, 256, 0, stream>>>(x_q,  xq16,  Mc * Ec / 8);
  cvt_kernel<<<2048, 256, 0, stream>>>(x_kv, xkv16, Mc * Ec / 8);
  cvt_kernel<<<2048, 256, 0, stream>>>(Wq, wq16, Ec * Ec / 8);
  cvt_kernel<<<2048, 256, 0, stream>>>(Wk, wk16, Ec * Ec / 8);
  cvt_kernel<<<2048, 256, 0, stream>>>(Wv, wv16, Ec * Ec / 8);
  cvt_kernel<<<2048, 256, 0, stream>>>(Wo, wo16, Ec * Ec / 8);

  const int gemmBlocks = (Mc / 256) * (Ec / 256); // 32*8 = 256
  gemm8<1><<<gemmBlocks, 512, 0, stream>>>(xq16,  wq16, bq, q0, Mc / 256);
  gemm8<1><<<gemmBlocks, 512, 0, stream>>>(xkv16, wk16, bk, k0, Mc / 256);
  gemm8<1><<<gemmBlocks, 512, 0, stream>>>(xkv16, wv16, bv, v0, Mc / 256);

  rope_kernel<<<2048, 256, 0, stream>>>(q0, angles, k_rope, 1);
  rope_kernel<<<2048, 256, 0, stream>>>(k0, angles, k_rope, 0);
  transpose_v<<<dim3(Sc / 64, Bc * Hc), 256, 0, stream>>>(v0, Vt);

  attn_kernel<<<1024, 256, 0, stream>>>(q0, k0, Vt, amask, causal, attn16);

  gemm8<0><<<gemmBlocks, 512, 0, stream>>>(attn16, wo16, bo, out, Mc / 256);
}